// Round 11
// baseline (148.119 us; speedup 1.0000x reference)
//
#include <hip/hip_runtime.h>

#define IN_DIM   256
#define HID_DIM  512
#define OUT_DIM  256
#define N_CHILD  8
#define BATCH    1024

#define SB    16   // samples per chunk
#define XPAD  20   // [k][s] LDS stride: 16B-aligned float4 groups
#define MAXCH 128  // sum ceil(n_a/16) <= (1024 + 64*15)/16 = 124 < 128

// ---------------- prep: sort samples by agent + zero atomic outputs ---------
// grid (5): block 0 = counting sort + chunk list (wave-wide prefix scan);
// blocks 1-4 = zero o_out/r_out (fused kernel accumulates via atomics).
// agent_indices may be int32 or int64 (jax_enable_x64): view as int32; if any
// odd word != 0 it's int32, else int64 (odd slots are zero high words).
extern "C" __global__ __launch_bounds__(1024)
void prep_sort(const int* __restrict__ raw, int* __restrict__ sorted,
               int* __restrict__ ch_agent, int* __restrict__ ch_start,
               int* __restrict__ ch_len, float* __restrict__ zdst)
{
    const int t = threadIdx.x;
    if (blockIdx.x > 0) {                         // zero o_out + r_out (1.06 MB)
        const int total4 = (BATCH * (OUT_DIM + N_CHILD)) / 4;   // 67584 float4
        const float4 z = make_float4(0.f, 0.f, 0.f, 0.f);
        for (int i = (blockIdx.x - 1) * 1024 + t; i < total4; i += 4 * 1024)
            ((float4*)zdst)[i] = z;
        return;
    }
    __shared__ int cnt[64], cnt2[64], start[64];
    __shared__ int is32, totch;
    if (t < 64) { cnt[t] = 0; cnt2[t] = 0; }
    if (t == 0) is32 = 0;
    __syncthreads();
    if (raw[2 * (t & 511) + 1] != 0) is32 = 1;   // benign shared race
    __syncthreads();
    const int a = (is32 ? raw[t] : raw[2 * t]) & 63;
    atomicAdd(&cnt[a], 1);
    __syncthreads();
    if (t < 64) {                                 // wave 0: dual prefix scan
        const int c   = cnt[t];
        const int nch = (c + SB - 1) / SB;
        int sc = c, sn = nch;
        #pragma unroll
        for (int d = 1; d < 64; d <<= 1) {
            const int vc = __shfl_up(sc, d);
            const int vn = __shfl_up(sn, d);
            if (t >= d) { sc += vc; sn += vn; }
        }
        const int off = sc - c;
        start[t] = off;
        const int chb = sn - nch;
        for (int p = 0, j = 0; p < c; p += SB, ++j) {
            ch_agent[chb + j] = t;
            ch_start[chb + j] = off + p;
            ch_len[chb + j]   = (c - p < SB) ? (c - p) : SB;
        }
        if (t == 63) totch = sn;
    }
    __syncthreads();
    if (t >= totch && t < MAXCH) ch_len[t] = 0;
    const int pos = start[a] + atomicAdd(&cnt2[a], 1);
    sorted[pos] = t;
}

// ---------------- fused: both layers + router, no inter-layer barrier -------
// grid (MAXCH, 8 tiles of 64 h-cols), 256 thr = 4 waves, 4 blk/CU (33 KB LDS).
// Block (chunk, y) computes h cols [64y,64y+64) for its 16 samples (layer 1),
// keeps the slice in LDS, then immediately computes the PARTIAL layer-2
// product  out += hT . W2[rows 64y..64y+64, :]  (atomicAdd into zeroed o_out)
// and the router partial. No global h round-trip, no device-wide barrier.
// lane map: cg=t&15 (4 cols), kq=(t>>4)&3 (in-wave K-split, kq-contiguous
// rows i*4+kq), wave w=t>>6 owns samples 4w..4w+3 (compute gated by len;
// inactive waves still stage tiles and hit every barrier).
extern "C" __global__ __launch_bounds__(256, 4)
void k_fused(const float* __restrict__ x, const float* __restrict__ W1,
             const float* __restrict__ b1, const float* __restrict__ W2,
             const float* __restrict__ b2, const float* __restrict__ rw,
             const int* __restrict__ sorted, const int* __restrict__ ch_agent,
             const int* __restrict__ ch_start, const int* __restrict__ ch_len,
             float* __restrict__ h_out, float* __restrict__ o_out,
             float* __restrict__ r_out)
{
    const int chunk = blockIdx.x;
    const int len = ch_len[chunk];
    if (len == 0) return;
    const int a  = ch_agent[chunk];
    const int cs = ch_start[chunk];
    const int t  = threadIdx.x;
    const int bcol = blockIdx.y * 64;        // h-col tile

    __shared__ float xT[IN_DIM * XPAD];      // 20 KB, [k][s], staged once
    __shared__ float hT[64 * XPAD];          // 5 KB, this block's h slice
    __shared__ float wS[32 * 64];            // 8 KB, staging tile (W1 then W2)
    __shared__ int   sid[SB];

    if (t < SB) sid[t] = sorted[cs + (t < len ? t : len - 1)];   // pad = dup
    __syncthreads();

    #pragma unroll
    for (int s = 0; s < SB; ++s)
        xT[t * XPAD + s] = x[(size_t)sid[s] * IN_DIM + t];       // coalesced

    const int cg = t & 15;
    const int kq = (t >> 4) & 3;
    const int w  = t >> 6;
    const bool act = (w * 4) < len;

    // ================= layer 1: h = relu(x @ W1 + b1), 64 cols ==============
    const float* Wb = W1 + (size_t)a * IN_DIM * HID_DIM + bcol;
    float acc[16];
    #pragma unroll
    for (int i = 0; i < 16; ++i) acc[i] = 0.f;

    for (int p = 0; p < IN_DIM / 32; ++p) {  // 8 passes of 32 k-rows
        __syncthreads();                     // wS reusable (covers xT at p==0)
        #pragma unroll
        for (int i = 0; i < 2; ++i) {        // stage 8 KB W1 tile
            const int id  = t + i * 256;
            const int row = id >> 4;         // 0..31
            const int c4  = (id & 15) * 4;
            *(float4*)(&wS[row * 64 + c4]) =
                *(const float4*)(Wb + (size_t)(p * 32 + row) * HID_DIM + c4);
        }
        __syncthreads();
        if (act) {
            #pragma unroll
            for (int i = 0; i < 8; ++i) {
                const int row = i * 4 + kq;
                const float4 wv = *(const float4*)(&wS[row * 64 + cg * 4]);
                const float4 xv = *(const float4*)(&xT[(p * 32 + row) * XPAD + w * 4]);
                const float wa[4] = {wv.x, wv.y, wv.z, wv.w};
                const float xa[4] = {xv.x, xv.y, xv.z, xv.w};
                #pragma unroll
                for (int c = 0; c < 4; ++c)
                    #pragma unroll
                    for (int s = 0; s < 4; ++s)
                        acc[c * 4 + s] = fmaf(wa[c], xa[s], acc[c * 4 + s]);
            }
        }
    }

    #pragma unroll
    for (int i = 0; i < 16; ++i) {           // reduce over kq (lane bits 4-5)
        acc[i] += __shfl_xor(acc[i], 16);
        acc[i] += __shfl_xor(acc[i], 32);
    }

    if (act && kq == 0) {                    // layer-1 epilogue + router
        const float4 bv = *(const float4*)(b1 + a * HID_DIM + bcol + cg * 4);
        const float ba[4] = {bv.x, bv.y, bv.z, bv.w};
        float hv[16];
        #pragma unroll
        for (int c = 0; c < 4; ++c)
            #pragma unroll
            for (int s = 0; s < 4; ++s)
                hv[c * 4 + s] = fmaxf(acc[c * 4 + s] + ba[c], 0.f);

        #pragma unroll
        for (int s = 0; s < 4; ++s) {        // h to global (dup-safe)
            float4 v = make_float4(hv[0 * 4 + s], hv[1 * 4 + s],
                                   hv[2 * 4 + s], hv[3 * 4 + s]);
            *(float4*)(h_out + (size_t)sid[w * 4 + s] * HID_DIM + bcol + cg * 4) = v;
        }
        #pragma unroll
        for (int c = 0; c < 4; ++c)          // h slice to LDS [kl][s]
            #pragma unroll
            for (int s = 0; s < 4; ++s)
                hT[(cg * 4 + c) * XPAD + (w * 4 + s)] = hv[c * 4 + s];

        float rp[32];                        // router partials [s][ch]
        #pragma unroll
        for (int i = 0; i < 32; ++i) rp[i] = 0.f;
        const float* rwa = rw + (size_t)a * HID_DIM * N_CHILD
                              + (size_t)(bcol + cg * 4) * N_CHILD;
        #pragma unroll
        for (int j = 0; j < 4; ++j)
            #pragma unroll
            for (int ch = 0; ch < 8; ++ch) {
                const float rv = rwa[j * N_CHILD + ch];
                #pragma unroll
                for (int s = 0; s < 4; ++s)
                    rp[s * 8 + ch] = fmaf(hv[j * 4 + s], rv, rp[s * 8 + ch]);
            }
        #pragma unroll
        for (int i = 0; i < 32; ++i) {       // reduce over cg (lane bits 0-3)
            rp[i] += __shfl_xor(rp[i], 1);
            rp[i] += __shfl_xor(rp[i], 2);
            rp[i] += __shfl_xor(rp[i], 4);
            rp[i] += __shfl_xor(rp[i], 8);
        }
        if (cg == 0) {
            #pragma unroll
            for (int s = 0; s < 4; ++s) {
                const int sg = w * 4 + s;
                if (sg < len) {              // strict gating for atomics
                    float* rdst = r_out + (size_t)sid[sg] * N_CHILD;
                    #pragma unroll
                    for (int ch = 0; ch < 8; ++ch)
                        atomicAdd(rdst + ch, rp[s * 8 + ch]);
                }
            }
        }
    }
    __syncthreads();                         // hT visible to all waves

    // ====== layer 2 partial: out += hT . W2[rows bcol..bcol+64, :] ==========
    const float* W2b = W2 + ((size_t)a * HID_DIM + bcol) * OUT_DIM;
    for (int q = 0; q < 4; ++q) {            // 4 out-col quarters of 64
        const int oc = q * 64;
        float ac2[16];
        #pragma unroll
        for (int i = 0; i < 16; ++i) ac2[i] = 0.f;

        for (int kp = 0; kp < 2; ++kp) {     // 2 passes of 32 k-rows
            __syncthreads();                 // wS reusable
            #pragma unroll
            for (int i = 0; i < 2; ++i) {    // stage 8 KB W2 tile
                const int id  = t + i * 256;
                const int row = id >> 4;     // 0..31
                const int c4  = (id & 15) * 4;
                *(float4*)(&wS[row * 64 + c4]) =
                    *(const float4*)(W2b + (size_t)(kp * 32 + row) * OUT_DIM + oc + c4);
            }
            __syncthreads();
            if (act) {
                #pragma unroll
                for (int i = 0; i < 8; ++i) {
                    const int row = i * 4 + kq;
                    const float4 wv = *(const float4*)(&wS[row * 64 + cg * 4]);
                    const float4 xv = *(const float4*)(&hT[(kp * 32 + row) * XPAD + w * 4]);
                    const float wa[4] = {wv.x, wv.y, wv.z, wv.w};
                    const float xa[4] = {xv.x, xv.y, xv.z, xv.w};
                    #pragma unroll
                    for (int c = 0; c < 4; ++c)
                        #pragma unroll
                        for (int s = 0; s < 4; ++s)
                            ac2[c * 4 + s] = fmaf(wa[c], xa[s], ac2[c * 4 + s]);
                }
            }
        }

        if (act) {
            #pragma unroll
            for (int i = 0; i < 16; ++i) {
                ac2[i] += __shfl_xor(ac2[i], 16);
                ac2[i] += __shfl_xor(ac2[i], 32);
            }
            if (kq == 0) {
                float4 bv = make_float4(0.f, 0.f, 0.f, 0.f);
                if (blockIdx.y == 0)         // bias added exactly once
                    bv = *(const float4*)(b2 + a * OUT_DIM + oc + cg * 4);
                #pragma unroll
                for (int s = 0; s < 4; ++s) {
                    const int g = w * 4 + s;
                    if (g < len) {           // strict gating: dups must not add
                        float* op = o_out + (size_t)sid[g] * OUT_DIM + oc + cg * 4;
                        atomicAdd(op + 0, ac2[0 * 4 + s] + bv.x);
                        atomicAdd(op + 1, ac2[1 * 4 + s] + bv.y);
                        atomicAdd(op + 2, ac2[2 * 4 + s] + bv.z);
                        atomicAdd(op + 3, ac2[3 * 4 + s] + bv.w);
                    }
                }
            }
        }
    }
}

extern "C" void kernel_launch(void* const* d_in, const int* in_sizes, int n_in,
                              void* d_out, int out_size, void* d_ws, size_t ws_size,
                              hipStream_t stream) {
    const float* x  = (const float*)d_in[0];
    const float* W1 = (const float*)d_in[1];
    const float* b1 = (const float*)d_in[2];
    const float* W2 = (const float*)d_in[3];
    const float* b2 = (const float*)d_in[4];
    const float* rw = (const float*)d_in[5];
    const int* raw  = (const int*)d_in[6];

    int* ws       = (int*)d_ws;
    int* sorted   = ws;            // [1024]
    int* ch_agent = ws + 1024;     // [128]
    int* ch_start = ws + 1152;     // [128]
    int* ch_len   = ws + 1280;     // [128]

    float* out   = (float*)d_out;
    float* h_out = out;                                   // [B, HID]
    float* o_out = h_out + (size_t)BATCH * HID_DIM;       // [B, OUT]
    float* r_out = o_out + (size_t)BATCH * OUT_DIM;       // [B, C]

    hipLaunchKernelGGL(prep_sort, dim3(5), dim3(1024), 0, stream,
                       raw, sorted, ch_agent, ch_start, ch_len, o_out);
    hipLaunchKernelGGL(k_fused, dim3(MAXCH, 8), dim3(256), 0, stream,
                       x, W1, b1, W2, b2, rw,
                       sorted, ch_agent, ch_start, ch_len,
                       h_out, o_out, r_out);
}